// Round 4
// baseline (301.022 us; speedup 1.0000x reference)
//
#include <hip/hip_runtime.h>
#include <hip/hip_bf16.h>
#include <stdint.h>

#define L_SEQ  4096
#define H_DIM  512
#define N_ST   64
#define N_B    8
#define N_CH   16     // chunks per sequence
#define T_CH   256    // chunk length  (N_CH * T_CH == L_SEQ)
#define K_GEMM 1024

typedef float  f32x4  __attribute__((ext_vector_type(4)));
typedef __bf16 bf16x8 __attribute__((ext_vector_type(8)));

// ---------------- K0: precompute A_bar, C*B_bar, A_bar^T ----------------
__global__ __launch_bounds__(256) void k_precompute(
    const float* __restrict__ A_log, const float* __restrict__ Bv,
    const float* __restrict__ C, const float* __restrict__ log_dt,
    const float* __restrict__ A_log_r, const float* __restrict__ B_r,
    const float* __restrict__ C_r,
    float* __restrict__ pA, float* __restrict__ pCB, float* __restrict__ pPW)
{
    int tid = blockIdx.x * 256 + threadIdx.x;      // 2*512*64 = 65536
    int n   = tid & 63;
    int h   = (tid >> 6) & 511;
    int dir = tid >> 15;
    float dt = expf(log_dt[h]);
    const float* Al = dir ? A_log_r : A_log;
    const float* Bp = dir ? B_r    : Bv;
    const float* Cp = dir ? C_r    : C;
    float eA = expf(Al[h * N_ST + n]);
    float Ab = expf(-dt * eA);
    float Bb = (1.0f - Ab) / eA * Bp[h * N_ST + n];
    pA[tid]  = Ab;                                  // tid == (dir*512+h)*64+n
    pCB[tid] = Cp[h * N_ST + n] * Bb;
    pPW[tid] = expf(-dt * eA * (float)T_CH);        // A_bar^T_CH exactly
}

// ---------------- Kw: W_bi f32 -> bf16 ----------------
__global__ __launch_bounds__(256) void k_convw(
    const float* __restrict__ W, __hip_bfloat16* __restrict__ Wbf)
{
    int tid = blockIdx.x * 256 + threadIdx.x;       // 512*1024
    Wbf[tid] = __float2bfloat16(W[tid]);
}

// ---------------- K1: per-chunk end states (zero init) ----------------
// chain = (dir, b, c, h), 4 lanes per chain (16 states each), h in low bits
#define PF1 8
__global__ __launch_bounds__(256, 4) void k_chunkstate(
    const float* __restrict__ u, const float* __restrict__ pA,
    float* __restrict__ S)
{
    int tid = blockIdx.x * 256 + threadIdx.x;       // 524288
    int q   = tid & 3;
    int h   = (tid >> 2) & 511;
    int c   = (tid >> 11) & 15;
    int b   = (tid >> 15) & 7;
    int dir = tid >> 18;

    const f32x4* Ap = (const f32x4*)(pA + (size_t)(dir * H_DIM + h) * N_ST + q * 16);
    float A[16], x[16];
    #pragma unroll
    for (int i = 0; i < 4; ++i) {
        f32x4 a = Ap[i];
        A[4*i+0] = a[0]; A[4*i+1] = a[1]; A[4*i+2] = a[2]; A[4*i+3] = a[3];
        x[4*i+0] = 0.f;  x[4*i+1] = 0.f;  x[4*i+2] = 0.f;  x[4*i+3] = 0.f;
    }

    int l0     = dir ? (L_SEQ - 1 - c * T_CH) : c * T_CH;
    int stride = dir ? -H_DIM : H_DIM;
    int off    = (b * L_SEQ + l0) * H_DIM + h;      // 32-bit offsets (u < 2^24 elems)

    float buf[PF1];
    #pragma unroll
    for (int k = 0; k < PF1; ++k) buf[k] = u[off + k * stride];

    for (int blk = 0; blk < T_CH / PF1 - 1; ++blk) {
        int noff = off + PF1 * stride;
        float nbuf[PF1];
        #pragma unroll
        for (int k = 0; k < PF1; ++k) nbuf[k] = u[noff + k * stride];
        #pragma unroll
        for (int k = 0; k < PF1; ++k) {
            float cur = buf[k];
            #pragma unroll
            for (int i = 0; i < 16; ++i) x[i] = fmaf(A[i], x[i], cur);
        }
        #pragma unroll
        for (int k = 0; k < PF1; ++k) buf[k] = nbuf[k];
        off = noff;
    }
    #pragma unroll
    for (int k = 0; k < PF1; ++k) {
        float cur = buf[k];
        #pragma unroll
        for (int i = 0; i < 16; ++i) x[i] = fmaf(A[i], x[i], cur);
    }

    f32x4* Sp = (f32x4*)(S + ((((size_t)dir * N_CH + c) * N_B + b) * H_DIM + h) * N_ST + q * 16);
    #pragma unroll
    for (int i = 0; i < 4; ++i) {
        f32x4 v; v[0] = x[4*i+0]; v[1] = x[4*i+1]; v[2] = x[4*i+2]; v[3] = x[4*i+3];
        Sp[i] = v;
    }
}

// ---------------- K2: inter-chunk scan (in place: S -> incoming states) ----------------
__global__ __launch_bounds__(256) void k_chunkscan(
    const float* __restrict__ pPW, float* __restrict__ S)
{
    int tid = blockIdx.x * 256 + threadIdx.x;       // 524288 = 2*8*512*64
    int n   = tid & 63;
    int h   = (tid >> 6) & 511;
    int b   = (tid >> 15) & 7;
    int dir = tid >> 18;
    float pw = pPW[((size_t)(dir * H_DIM + h)) * N_ST + n];
    float X = 0.f;
    for (int c = 0; c < N_CH; ++c) {
        size_t a = ((((size_t)dir * N_CH + c) * N_B + b) * H_DIM + h) * N_ST + n;
        float tmp = S[a];
        S[a] = X;                 // incoming state for chunk c
        X = fmaf(pw, X, tmp);
    }
}

// ---------------- K3: full scan + output (bf16 ycat) ----------------
// 4 lanes per chain, 16 states each; PF-deep u prefetch; 32-bit offsets.
#define PF3 8
__global__ __launch_bounds__(256, 4) void k_scanout(
    const float* __restrict__ u, const float* __restrict__ pA,
    const float* __restrict__ pCB, const float* __restrict__ Dv,
    const float* __restrict__ S, __hip_bfloat16* __restrict__ yc)
{
    int tid = blockIdx.x * 256 + threadIdx.x;       // 524288
    int q   = tid & 3;
    int h   = (tid >> 2) & 511;
    int c   = (tid >> 11) & 15;
    int b   = (tid >> 15) & 7;
    int dir = tid >> 18;

    const f32x4* Ap  = (const f32x4*)(pA  + (size_t)(dir * H_DIM + h) * N_ST + q * 16);
    const f32x4* CBp = (const f32x4*)(pCB + (size_t)(dir * H_DIM + h) * N_ST + q * 16);
    const f32x4* Sp  = (const f32x4*)(S + ((((size_t)dir * N_CH + c) * N_B + b) * H_DIM + h) * N_ST + q * 16);

    float A[16], CB[16], x[16];
    #pragma unroll
    for (int i = 0; i < 4; ++i) {
        f32x4 a = Ap[i], cb = CBp[i], xs = Sp[i];
        A[4*i+0]=a[0];  A[4*i+1]=a[1];  A[4*i+2]=a[2];  A[4*i+3]=a[3];
        CB[4*i+0]=cb[0]; CB[4*i+1]=cb[1]; CB[4*i+2]=cb[2]; CB[4*i+3]=cb[3];
        x[4*i+0]=xs[0]; x[4*i+1]=xs[1]; x[4*i+2]=xs[2]; x[4*i+3]=xs[3];
    }
    float Dh = Dv[h];

    int l0     = dir ? (L_SEQ - 1 - c * T_CH) : c * T_CH;
    int stride = dir ? -H_DIM : H_DIM;
    int ostr   = dir ? -(2 * H_DIM) : (2 * H_DIM);
    int off    = (b * L_SEQ + l0) * H_DIM + h;
    int ooff   = (b * L_SEQ + l0) * (2 * H_DIM) + dir * H_DIM + h;

    float buf[PF3];
    #pragma unroll
    for (int k = 0; k < PF3; ++k) buf[k] = u[off + k * stride];

    for (int blk = 0; blk < T_CH / PF3; ++blk) {
        int noff = off + PF3 * stride;
        float nbuf[PF3];
        if (blk < T_CH / PF3 - 1) {
            #pragma unroll
            for (int k = 0; k < PF3; ++k) nbuf[k] = u[noff + k * stride];
        }
        #pragma unroll
        for (int k = 0; k < PF3; ++k) {
            float cur = buf[k];
            float p0 = 0.f, p1 = 0.f, p2 = 0.f, p3 = 0.f;
            #pragma unroll
            for (int i = 0; i < 4; ++i) {
                x[4*i+0] = fmaf(A[4*i+0], x[4*i+0], cur);
                x[4*i+1] = fmaf(A[4*i+1], x[4*i+1], cur);
                x[4*i+2] = fmaf(A[4*i+2], x[4*i+2], cur);
                x[4*i+3] = fmaf(A[4*i+3], x[4*i+3], cur);
                p0 = fmaf(CB[4*i+0], x[4*i+0], p0);
                p1 = fmaf(CB[4*i+1], x[4*i+1], p1);
                p2 = fmaf(CB[4*i+2], x[4*i+2], p2);
                p3 = fmaf(CB[4*i+3], x[4*i+3], p3);
            }
            float s = (p0 + p1) + (p2 + p3);
            s += __shfl_xor(s, 1);
            s += __shfl_xor(s, 2);              // all 4 lanes now hold full 64-state sum
            yc[ooff] = __float2bfloat16(fmaf(Dh, cur, s));  // same value, same addr
            ooff += ostr;
        }
        if (blk < T_CH / PF3 - 1) {
            #pragma unroll
            for (int k = 0; k < PF3; ++k) buf[k] = nbuf[k];
        }
        off = noff;
    }
}

// ---------------- K4: out = ycat(bf16) @ W(bf16)^T + bias, f32 out ----------------
// A: [32768,1024] row-major, B: [512,1024] row-major (B^T GEMM), out: [32768,512]
// m97-style: global_load_lds width-16 staging into linear LDS tiles.
__global__ __launch_bounds__(256) void k_gemm(
    const __hip_bfloat16* __restrict__ A, const __hip_bfloat16* __restrict__ B,
    const float* __restrict__ bias, float* __restrict__ out)
{
    __shared__ __hip_bfloat16 As[128][32];
    __shared__ __hip_bfloat16 Bs[128][32];
    int t  = threadIdx.x;
    int l  = t & 63, w = t >> 6;
    int lr = l & 15, lg = l >> 4;
    int mBase = blockIdx.y * 128;
    int nBase = blockIdx.x * 128;
    int wr = (w >> 1) * 64, wc = (w & 1) * 64;

    int rowL = w * 16 + (l >> 2);       // i=0 row (add 64 for i=1)
    int kb   = (l & 3) * 8;

    f32x4 acc[4][4] = {};

    for (int kt = 0; kt < K_GEMM; kt += 32) {
        __syncthreads();
        {
            const __hip_bfloat16* ga0 = A + (size_t)(mBase + rowL) * K_GEMM + kt + kb;
            const __hip_bfloat16* ga1 = A + (size_t)(mBase + 64 + rowL) * K_GEMM + kt + kb;
            const __hip_bfloat16* gb0 = B + (size_t)(nBase + rowL) * K_GEMM + kt + kb;
            const __hip_bfloat16* gb1 = B + (size_t)(nBase + 64 + rowL) * K_GEMM + kt + kb;
            char* la0 = ((char*)&As[0][0]) + (w * 64) * 16;
            char* la1 = ((char*)&As[0][0]) + (256 + w * 64) * 16;
            char* lb0 = ((char*)&Bs[0][0]) + (w * 64) * 16;
            char* lb1 = ((char*)&Bs[0][0]) + (256 + w * 64) * 16;
            __builtin_amdgcn_global_load_lds(
                (const __attribute__((address_space(1))) void*)ga0,
                (__attribute__((address_space(3))) void*)la0, 16, 0, 0);
            __builtin_amdgcn_global_load_lds(
                (const __attribute__((address_space(1))) void*)ga1,
                (__attribute__((address_space(3))) void*)la1, 16, 0, 0);
            __builtin_amdgcn_global_load_lds(
                (const __attribute__((address_space(1))) void*)gb0,
                (__attribute__((address_space(3))) void*)lb0, 16, 0, 0);
            __builtin_amdgcn_global_load_lds(
                (const __attribute__((address_space(1))) void*)gb1,
                (__attribute__((address_space(3))) void*)lb1, 16, 0, 0);
        }
        __syncthreads();
        bf16x8 af[4], bfv[4];
        #pragma unroll
        for (int m = 0; m < 4; ++m) af[m]  = *(const bf16x8*)&As[wr + m * 16 + lr][lg * 8];
        #pragma unroll
        for (int n = 0; n < 4; ++n) bfv[n] = *(const bf16x8*)&Bs[wc + n * 16 + lr][lg * 8];
        #pragma unroll
        for (int m = 0; m < 4; ++m)
            #pragma unroll
            for (int n = 0; n < 4; ++n)
                acc[m][n] = __builtin_amdgcn_mfma_f32_16x16x32_bf16(af[m], bfv[n], acc[m][n], 0, 0, 0);
    }

    #pragma unroll
    for (int n = 0; n < 4; ++n) {
        int colg = nBase + wc + n * 16 + lr;
        float bv = bias[colg];
        #pragma unroll
        for (int m = 0; m < 4; ++m) {
            int rowg = mBase + wr + m * 16 + lg * 4;
            #pragma unroll
            for (int r = 0; r < 4; ++r)
                out[(size_t)(rowg + r) * H_DIM + colg] = acc[m][n][r] + bv;
        }
    }
}

extern "C" void kernel_launch(void* const* d_in, const int* in_sizes, int n_in,
                              void* d_out, int out_size, void* d_ws, size_t ws_size,
                              hipStream_t stream)
{
    const float* u       = (const float*)d_in[0];
    const float* A_log   = (const float*)d_in[1];
    const float* Bv      = (const float*)d_in[2];
    const float* C       = (const float*)d_in[3];
    const float* D       = (const float*)d_in[4];
    const float* log_dt  = (const float*)d_in[5];
    const float* A_log_r = (const float*)d_in[6];
    const float* B_r     = (const float*)d_in[7];
    const float* C_r     = (const float*)d_in[8];
    const float* W_bi    = (const float*)d_in[9];
    const float* b_bi    = (const float*)d_in[10];
    float* out = (float*)d_out;

    char* ws = (char*)d_ws;
    float* pA  = (float*)(ws);                       // 65536 f
    float* pCB = (float*)(ws + 262144);              // 65536 f
    float* pPW = (float*)(ws + 524288);              // 65536 f
    float* S   = (float*)(ws + 786432);              // 8388608 f (32 MB)
    __hip_bfloat16* yc  = (__hip_bfloat16*)(ws + 786432 + 33554432);            // 64 MB
    __hip_bfloat16* Wbf = (__hip_bfloat16*)(ws + 786432 + 33554432 + 67108864); // 1 MB

    k_precompute<<<256,  256, 0, stream>>>(A_log, Bv, C, log_dt, A_log_r, B_r, C_r, pA, pCB, pPW);
    k_convw     <<<2048, 256, 0, stream>>>(W_bi, Wbf);
    k_chunkstate<<<2048, 256, 0, stream>>>(u, pA, S);
    k_chunkscan <<<2048, 256, 0, stream>>>(pPW, S);
    k_scanout   <<<2048, 256, 0, stream>>>(u, pA, pCB, D, S, yc);
    dim3 g(4, 256);
    k_gemm<<<g, 256, 0, stream>>>(yc, Wbf, b_bi, out);
}

// Round 5
// 262.641 us; speedup vs baseline: 1.1461x; 1.1461x over previous
//
#include <hip/hip_runtime.h>
#include <hip/hip_bf16.h>
#include <stdint.h>

#define L_SEQ  4096
#define H_DIM  512
#define N_ST   64
#define N_B    8
#define N_CH   16
#define T_CH   256
#define K_GEMM 1024

typedef float  f32x4  __attribute__((ext_vector_type(4)));
typedef __bf16 bf16x8 __attribute__((ext_vector_type(8)));
typedef __bf16 bf16x4 __attribute__((ext_vector_type(4)));
typedef unsigned short u16x8 __attribute__((ext_vector_type(8)));

#define GLOAD16(g, l) __builtin_amdgcn_global_load_lds( \
    (const __attribute__((address_space(1))) void*)(g), \
    (__attribute__((address_space(3))) void*)(l), 16, 0, 0)

// ---------------- K0: precompute A_bar, C*B_bar, A_bar^T, log2(A_bar) ----------------
__global__ __launch_bounds__(256) void k_precompute(
    const float* __restrict__ A_log, const float* __restrict__ Bv,
    const float* __restrict__ C, const float* __restrict__ log_dt,
    const float* __restrict__ A_log_r, const float* __restrict__ B_r,
    const float* __restrict__ C_r,
    float* __restrict__ pA, float* __restrict__ pCB, float* __restrict__ pPW,
    float* __restrict__ pLG)
{
    int tid = blockIdx.x * 256 + threadIdx.x;      // 2*512*64
    int n   = tid & 63;
    int h   = (tid >> 6) & 511;
    int dir = tid >> 15;
    float dt = expf(log_dt[h]);
    const float* Al = dir ? A_log_r : A_log;
    const float* Bp = dir ? B_r    : Bv;
    const float* Cp = dir ? C_r    : C;
    float eA = expf(Al[h * N_ST + n]);
    float Ab = expf(-dt * eA);
    float Bb = (1.0f - Ab) / eA * Bp[h * N_ST + n];
    pA[tid]  = Ab;
    pCB[tid] = Cp[h * N_ST + n] * Bb;
    pPW[tid] = expf(-dt * eA * (float)T_CH);
    pLG[tid] = -dt * eA * 1.44269504088896f;       // log2(A_bar)
}

// ---------------- Kw: W_bi f32 -> bf16 ----------------
__global__ __launch_bounds__(256) void k_convw(
    const float* __restrict__ W, __bf16* __restrict__ Wbf)
{
    int tid = blockIdx.x * 256 + threadIdx.x;
    Wbf[tid] = (__bf16)W[tid];
}

// ---------------- k_kk: conv kernel taps kk[dirh][d] = sum_n CB_n A_n^d ----------------
__global__ __launch_bounds__(256) void k_kk(
    const float* __restrict__ pCB, const float* __restrict__ pLG,
    float* __restrict__ kk)
{
    __shared__ float scb[64], slg[64];
    int dirh = blockIdx.x;           // 0..1023
    int d = threadIdx.x;             // 0..255
    if (d < 64) { scb[d] = pCB[dirh * 64 + d]; slg[d] = pLG[dirh * 64 + d]; }
    __syncthreads();
    float s = 0.f;
    #pragma unroll
    for (int n = 0; n < 64; ++n) s += scb[n] * exp2f((float)d * slg[n]);
    kk[dirh * 256 + d] = s;
}

// ---------------- k_ut: u [b,l,h] f32 -> ut [h][b][l] bf16 ----------------
__global__ __launch_bounds__(256) void k_ut(
    const float* __restrict__ u, __bf16* __restrict__ ut)
{
    __shared__ float tl[32][65];
    int blk = blockIdx.x;            // 128 l-tiles * 8 h-tiles * 8 b
    int lt = blk & 127, ht = (blk >> 7) & 7, b = blk >> 10;
    int t = threadIdx.x;
    int ho = t & 63, li = t >> 6;
    #pragma unroll
    for (int it = 0; it < 8; ++it) {
        int l = it * 4 + li;
        tl[l][ho] = u[(size_t)(b * L_SEQ + lt * 32 + l) * H_DIM + ht * 64 + ho];
    }
    __syncthreads();
    int hh = t >> 2, lrun = (t & 3) * 8;
    bf16x8 v;
    #pragma unroll
    for (int i = 0; i < 8; ++i) v[i] = (__bf16)tl[lrun + i][hh];
    *(bf16x8*)(ut + (size_t)(ht * 64 + hh) * 32768 + b * 4096 + lt * 32 + lrun) = v;
}

// ---------------- K1: per-chunk end states from ut (bf16 streaming) ----------------
template<int DIR>
__device__ __forceinline__ void state_body(
    int tid, const __bf16* __restrict__ ut, const float* __restrict__ pA,
    __bf16* __restrict__ S)
{
    int q = tid & 3, h = (tid >> 2) & 511, c = (tid >> 11) & 15, b = (tid >> 15) & 7;
    const f32x4* Ap = (const f32x4*)(pA + (size_t)(DIR * 512 + h) * 64 + q * 16);
    float A[16], x[16];
    #pragma unroll
    for (int i = 0; i < 4; ++i) {
        f32x4 a = Ap[i];
        A[4*i+0]=a[0]; A[4*i+1]=a[1]; A[4*i+2]=a[2]; A[4*i+3]=a[3];
        x[4*i+0]=0.f;  x[4*i+1]=0.f;  x[4*i+2]=0.f;  x[4*i+3]=0.f;
    }
    int off = h * 32768 + b * 4096 + (DIR ? (c * 256 + 248) : c * 256);
    const int vstep = DIR ? -8 : 8;
    bf16x8 v = *(const bf16x8*)(ut + off);
    for (int blk = 0; blk < 31; ++blk) {
        off += vstep;
        bf16x8 nv = *(const bf16x8*)(ut + off);
        #pragma unroll
        for (int jj = 0; jj < 8; ++jj) {
            float cur = (float)v[DIR ? 7 - jj : jj];
            #pragma unroll
            for (int i = 0; i < 16; ++i) x[i] = fmaf(A[i], x[i], cur);
        }
        v = nv;
    }
    #pragma unroll
    for (int jj = 0; jj < 8; ++jj) {
        float cur = (float)v[DIR ? 7 - jj : jj];
        #pragma unroll
        for (int i = 0; i < 16; ++i) x[i] = fmaf(A[i], x[i], cur);
    }
    size_t soff = ((((size_t)DIR * N_CH + c) * N_B + b) * H_DIM + h) * N_ST + q * 16;
    bf16x8 o0, o1;
    #pragma unroll
    for (int i = 0; i < 8; ++i) { o0[i] = (__bf16)x[i]; o1[i] = (__bf16)x[8 + i]; }
    *(bf16x8*)(S + soff) = o0;
    *(bf16x8*)(S + soff + 8) = o1;
}

__global__ __launch_bounds__(256) void k_state(
    const __bf16* __restrict__ ut, const float* __restrict__ pA,
    __bf16* __restrict__ S)
{
    int tid = blockIdx.x * 256 + threadIdx.x;      // 524288
    if (tid >> 18) state_body<1>(tid, ut, pA, S);
    else           state_body<0>(tid, ut, pA, S);
}

// ---------------- K2: inter-chunk scan (bf16 S, in place) ----------------
__global__ __launch_bounds__(256) void k_chunkscan(
    const float* __restrict__ pPW, __bf16* __restrict__ S)
{
    int tid = blockIdx.x * 256 + threadIdx.x;      // 524288
    int n   = tid & 63;
    int h   = (tid >> 6) & 511;
    int b   = (tid >> 15) & 7;
    int dir = tid >> 18;
    float pw = pPW[((size_t)(dir * H_DIM + h)) * N_ST + n];
    float X = 0.f;
    for (int c = 0; c < N_CH; ++c) {
        size_t a = ((((size_t)dir * N_CH + c) * N_B + b) * H_DIM + h) * N_ST + n;
        float tmp = (float)S[a];
        S[a] = (__bf16)X;
        X = fmaf(pw, X, tmp);
    }
}

// ---------------- k_conv: MFMA chunk conv  y = Toep(k)@u + G@x0 + D*u ----------------
template<int DIR>
__device__ __forceinline__ void conv_body(
    int h, int t,
    const float* __restrict__ kk, const float* __restrict__ pLG,
    const float* __restrict__ pCB, const float* __restrict__ Dv,
    const __bf16* __restrict__ ut, const __bf16* __restrict__ S,
    __bf16* __restrict__ ycT,
    unsigned short* kkb, __bf16 (*G)[72], __bf16* BtB, float* slg, float* scb)
{
    int dirh = DIR * 512 + h;
    int lane = t & 63, w = t >> 6;
    int lr = lane & 15, lg = lane >> 4;
    int wr = (w >> 1) * 128, wc = (w & 1) * 64;

    // init kkb (taps, zero-padded both sides), slg/scb
    for (int i = t; i < 544; i += 256) {
        int d = i - 272;
        float kv = (d >= 0 && d < 256) ? kk[dirh * 256 + d] : 0.f;
        kkb[i] = __builtin_bit_cast(unsigned short, (__bf16)kv);
    }
    if (t < 64) { slg[t] = pLG[dirh * 64 + t]; scb[t] = pCB[dirh * 64 + t]; }
    __syncthreads();
    // build G[l][n] = CB_n * A_n^e  (e = l+1 fwd, T-l rev)
    {
        int l = t;
        float e = DIR ? (float)(256 - l) : (float)(l + 1);
        #pragma unroll
        for (int n0 = 0; n0 < 64; n0 += 8) {
            bf16x8 g;
            #pragma unroll
            for (int i = 0; i < 8; ++i)
                g[i] = (__bf16)(scb[n0 + i] * exp2f(e * slg[n0 + i]));
            *(bf16x8*)&G[l][n0] = g;
        }
    }

    f32x4 acc[8][4] = {};

    int colT = t & 127;
    int jsub = t >> 7;   // wave-uniform
    size_t ubase = (size_t)h * 32768 + (colT >> 4) * 4096 + (colT & 15) * 256;

    // Bt layout: [buf][4][128][8] bf16, dest lane-linear for global_load_lds
    #define STAGE(jt, bfi) do { \
        GLOAD16(ut + ubase + (jt) * 32 + jsub * 8, \
                (char*)BtB + (bfi) * 8192 + jsub * 2048 + colT * 16); \
        GLOAD16(ut + ubase + (jt) * 32 + (jsub + 2) * 8, \
                (char*)BtB + (bfi) * 8192 + (jsub + 2) * 2048 + colT * 16); \
    } while (0)

    STAGE(0, 0);
    int bfc = 0;
    #pragma unroll
    for (int jt = 0; jt < 8; ++jt) {
        if (jt < 7) STAGE(jt + 1, bfc ^ 1);
        __syncthreads();
        bf16x8 bv[4];
        #pragma unroll
        for (int n_ = 0; n_ < 4; ++n_)
            bv[n_] = *(const bf16x8*)((char*)BtB + bfc * 8192 + lg * 2048
                                      + (wc + n_ * 16 + lr) * 16);
        #pragma unroll
        for (int m = 0; m < 8; ++m) {
            int l = wr + m * 16 + lr;
            int base = DIR ? (272 + jt * 32 + lg * 8 - l) : (272 + l - jt * 32 - lg * 8);
            u16x8 tmp;
            #pragma unroll
            for (int e = 0; e < 8; ++e)
                tmp[e] = kkb[DIR ? (base + e) : (base - e)];
            bf16x8 av = __builtin_bit_cast(bf16x8, tmp);
            #pragma unroll
            for (int n_ = 0; n_ < 4; ++n_)
                acc[m][n_] = __builtin_amdgcn_mfma_f32_16x16x32_bf16(av, bv[n_], acc[m][n_], 0, 0, 0);
        }
        __syncthreads();
        bfc ^= 1;
    }
    #undef STAGE

    // state-injection K-steps (n dimension), B-frags straight from global S
    #pragma unroll
    for (int nt = 0; nt < 2; ++nt) {
        bf16x8 bvn[4];
        #pragma unroll
        for (int n_ = 0; n_ < 4; ++n_) {
            int col = wc + n_ * 16 + lr;
            int b = col >> 4, cf = col & 15;
            int cS = DIR ? (15 - cf) : cf;
            size_t soff = ((((size_t)DIR * N_CH + cS) * N_B + b) * H_DIM + h) * N_ST
                          + nt * 32 + lg * 8;
            bvn[n_] = *(const bf16x8*)(S + soff);
        }
        #pragma unroll
        for (int m = 0; m < 8; ++m) {
            int l = wr + m * 16 + lr;
            bf16x8 av = *(const bf16x8*)&G[l][nt * 32 + lg * 8];
            #pragma unroll
            for (int n_ = 0; n_ < 4; ++n_)
                acc[m][n_] = __builtin_amdgcn_mfma_f32_16x16x32_bf16(av, bvn[n_], acc[m][n_], 0, 0, 0);
        }
    }

    // epilogue: + D*u, write ycT[dirh][m]  (coalesced 32B runs)
    float Dh = Dv[h];
    #pragma unroll
    for (int n_ = 0; n_ < 4; ++n_) {
        int col = wc + n_ * 16 + lr;
        size_t mb = (size_t)(col >> 4) * 4096 + (col & 15) * 256;
        #pragma unroll
        for (int m = 0; m < 8; ++m) {
            int l0 = wr + m * 16 + lg * 4;
            bf16x4 uv = *(const bf16x4*)(ut + (size_t)h * 32768 + mb + l0);
            bf16x4 o;
            #pragma unroll
            for (int r = 0; r < 4; ++r)
                o[r] = (__bf16)(acc[m][n_][r] + Dh * (float)uv[r]);
            *(bf16x4*)(ycT + (size_t)dirh * 32768 + mb + l0) = o;
        }
    }
}

__global__ __launch_bounds__(256) void k_conv(
    const float* __restrict__ kk, const float* __restrict__ pLG,
    const float* __restrict__ pCB, const float* __restrict__ Dv,
    const __bf16* __restrict__ ut, const __bf16* __restrict__ S,
    __bf16* __restrict__ ycT)
{
    __shared__ unsigned short kkb[544];
    __shared__ __bf16 G[256][72];
    __shared__ __bf16 Bt[2][4][128][8];
    __shared__ float slg[64], scb[64];
    int h = blockIdx.x & 511;
    int t = threadIdx.x;
    if (blockIdx.x >> 9)
        conv_body<1>(h, t, kk, pLG, pCB, Dv, ut, S, ycT, kkb, G, &Bt[0][0][0][0], slg, scb);
    else
        conv_body<0>(h, t, kk, pLG, pCB, Dv, ut, S, ycT, kkb, G, &Bt[0][0][0][0], slg, scb);
}

// ---------------- K4: out = ycat @ W^T + bias ; A read from ycT[k][m] ----------------
__global__ __launch_bounds__(256) void k_gemm(
    const __bf16* __restrict__ ycT, const __bf16* __restrict__ B,
    const float* __restrict__ bias, float* __restrict__ out)
{
    __shared__ __bf16 As[4][128][8];    // [k>>3][m][k&7], XOR-swizzled
    __shared__ __bf16 Bs[128][32];
    int t  = threadIdx.x;
    int l  = t & 63, w = t >> 6;
    int lr = l & 15, lg = l >> 4;
    int mBase = blockIdx.y * 128;
    int nBase = blockIdx.x * 128;
    int wr = (w >> 1) * 64, wc = (w & 1) * 64;

    int rowL = w * 16 + (l >> 2);
    int kb   = (l & 3) * 8;

    int sT  = t & 15;           // m-group (8 rows each)
    int skk = t >> 4;           // 0..15
    int swz = (sT & 7) << 4;

    char* AsB = (char*)&As[0][0][0];
    f32x4 acc[4][4] = {};

    for (int kt = 0; kt < K_GEMM; kt += 32) {
        __syncthreads();
        {   // B tile via global_load_lds (linear)
            const __bf16* gb0 = B + (size_t)(nBase + rowL) * K_GEMM + kt + kb;
            const __bf16* gb1 = B + (size_t)(nBase + 64 + rowL) * K_GEMM + kt + kb;
            GLOAD16(gb0, ((char*)&Bs[0][0]) + (w * 64) * 16);
            GLOAD16(gb1, ((char*)&Bs[0][0]) + (256 + w * 64) * 16);
        }
        // A tile from ycT[k][m]: reg-staged 16x8 transpose, swizzled writes
        #pragma unroll
        for (int p = 0; p < 2; ++p) {
            int kk_ = skk + p * 16;
            u16x8 av = *(const u16x8*)(ycT + (size_t)(kt + kk_) * 32768 + mBase + sT * 8);
            int kgrp = kk_ >> 3, ke = kk_ & 7;
            #pragma unroll
            for (int i = 0; i < 8; ++i) {
                int off = ((kgrp * 128 + sT * 8 + i) * 16 + ke * 2) ^ swz;
                *(unsigned short*)(AsB + off) = av[i];
            }
        }
        __syncthreads();
        bf16x8 af[4], bfv[4];
        #pragma unroll
        for (int m = 0; m < 4; ++m) {
            int row = wr + m * 16 + lr;
            int off = ((lg * 128 + row) * 16) ^ (((row >> 3) & 7) << 4);
            af[m] = *(const bf16x8*)(AsB + off);
        }
        #pragma unroll
        for (int n = 0; n < 4; ++n) bfv[n] = *(const bf16x8*)&Bs[wc + n * 16 + lr][lg * 8];
        #pragma unroll
        for (int m = 0; m < 4; ++m)
            #pragma unroll
            for (int n = 0; n < 4; ++n)
                acc[m][n] = __builtin_amdgcn_mfma_f32_16x16x32_bf16(af[m], bfv[n], acc[m][n], 0, 0, 0);
    }

    #pragma unroll
    for (int n = 0; n < 4; ++n) {
        int colg = nBase + wc + n * 16 + lr;
        float bv = bias[colg];
        #pragma unroll
        for (int m = 0; m < 4; ++m) {
            int rowg = mBase + wr + m * 16 + lg * 4;
            #pragma unroll
            for (int r = 0; r < 4; ++r)
                out[(size_t)(rowg + r) * H_DIM + colg] = acc[m][n][r] + bv;
        }
    }
}

extern "C" void kernel_launch(void* const* d_in, const int* in_sizes, int n_in,
                              void* d_out, int out_size, void* d_ws, size_t ws_size,
                              hipStream_t stream)
{
    const float* u       = (const float*)d_in[0];
    const float* A_log   = (const float*)d_in[1];
    const float* Bv      = (const float*)d_in[2];
    const float* C       = (const float*)d_in[3];
    const float* D       = (const float*)d_in[4];
    const float* log_dt  = (const float*)d_in[5];
    const float* A_log_r = (const float*)d_in[6];
    const float* B_r     = (const float*)d_in[7];
    const float* C_r     = (const float*)d_in[8];
    const float* W_bi    = (const float*)d_in[9];
    const float* b_bi    = (const float*)d_in[10];
    float* out = (float*)d_out;

    char* ws = (char*)d_ws;
    float* pA   = (float*)(ws + 0x000000);   // 256 KiB
    float* pCB  = (float*)(ws + 0x040000);
    float* pPW  = (float*)(ws + 0x080000);
    float* pLG  = (float*)(ws + 0x0C0000);
    float* kk   = (float*)(ws + 0x100000);   // 1 MiB
    __bf16* Wbf = (__bf16*)(ws + 0x200000);  // 1 MiB
    __bf16* S   = (__bf16*)(ws + 0x300000);  // 16 MiB
    __bf16* ut  = (__bf16*)(ws + 0x1300000); // 32 MiB
    __bf16* ycT = (__bf16*)(ws + 0x3300000); // 64 MiB  (end 115 MiB)

    k_precompute<<<256,  256, 0, stream>>>(A_log, Bv, C, log_dt, A_log_r, B_r, C_r,
                                           pA, pCB, pPW, pLG);
    k_convw     <<<2048, 256, 0, stream>>>(W_bi, Wbf);
    k_kk        <<<1024, 256, 0, stream>>>(pCB, pLG, kk);
    k_ut        <<<8192, 256, 0, stream>>>(u, ut);
    k_state     <<<2048, 256, 0, stream>>>(ut, pA, S);
    k_chunkscan <<<2048, 256, 0, stream>>>(pPW, S);
    k_conv      <<<1024, 256, 0, stream>>>(kk, pLG, pCB, D, ut, S, ycT);
    dim3 g(4, 256);
    k_gemm      <<<g,    256, 0, stream>>>(ycT, Wbf, b_bi, out);
}

// Round 6
// 231.537 us; speedup vs baseline: 1.3001x; 1.1343x over previous
//
#include <hip/hip_runtime.h>
#include <hip/hip_bf16.h>
#include <stdint.h>

#define L_SEQ  4096
#define H_DIM  512
#define N_ST   64
#define N_B    8
#define N_CH   16
#define T_CH   256
#define K_GEMM 1024

typedef float  f32x4  __attribute__((ext_vector_type(4)));
typedef __bf16 bf16x8 __attribute__((ext_vector_type(8)));
typedef __bf16 bf16x4 __attribute__((ext_vector_type(4)));
typedef unsigned short u16x8 __attribute__((ext_vector_type(8)));
typedef unsigned long long ull;

#define GLOAD16(g, l) __builtin_amdgcn_global_load_lds( \
    (const __attribute__((address_space(1))) void*)(g), \
    (__attribute__((address_space(3))) void*)(l), 16, 0, 0)

// ---------------- K0: precompute A_bar, C*B_bar, A_bar^T, log2(A_bar) ----------------
__global__ __launch_bounds__(256) void k_precompute(
    const float* __restrict__ A_log, const float* __restrict__ Bv,
    const float* __restrict__ C, const float* __restrict__ log_dt,
    const float* __restrict__ A_log_r, const float* __restrict__ B_r,
    const float* __restrict__ C_r,
    float* __restrict__ pA, float* __restrict__ pCB, float* __restrict__ pPW,
    float* __restrict__ pLG)
{
    int tid = blockIdx.x * 256 + threadIdx.x;      // 2*512*64
    int n   = tid & 63;
    int h   = (tid >> 6) & 511;
    int dir = tid >> 15;
    float dt = expf(log_dt[h]);
    const float* Al = dir ? A_log_r : A_log;
    const float* Bp = dir ? B_r    : Bv;
    const float* Cp = dir ? C_r    : C;
    float eA = expf(Al[h * N_ST + n]);
    float Ab = expf(-dt * eA);
    float Bb = (1.0f - Ab) / eA * Bp[h * N_ST + n];
    pA[tid]  = Ab;
    pCB[tid] = Cp[h * N_ST + n] * Bb;
    pPW[tid] = expf(-dt * eA * (float)T_CH);
    pLG[tid] = -dt * eA * 1.44269504088896f;       // log2(A_bar)
}

// ---------------- Kw: W_bi f32 -> bf16 ----------------
__global__ __launch_bounds__(256) void k_convw(
    const float* __restrict__ W, __bf16* __restrict__ Wbf)
{
    int tid = blockIdx.x * 256 + threadIdx.x;
    Wbf[tid] = (__bf16)W[tid];
}

// ---------------- k_kk: conv kernel taps kk[dirh][d] = sum_n CB_n A_n^d ----------------
__global__ __launch_bounds__(256) void k_kk(
    const float* __restrict__ pCB, const float* __restrict__ pLG,
    float* __restrict__ kk)
{
    __shared__ float scb[64], slg[64];
    int dirh = blockIdx.x;           // 0..1023
    int d = threadIdx.x;             // 0..255
    if (d < 64) { scb[d] = pCB[dirh * 64 + d]; slg[d] = pLG[dirh * 64 + d]; }
    __syncthreads();
    float s = 0.f;
    #pragma unroll
    for (int n = 0; n < 64; ++n) s += scb[n] * exp2f((float)d * slg[n]);
    kk[dirh * 256 + d] = s;
}

// ---------------- k_ut: u [b,l,h] f32 -> ut [h][b][l] bf16 ----------------
__global__ __launch_bounds__(256) void k_ut(
    const float* __restrict__ u, __bf16* __restrict__ ut)
{
    __shared__ float tl[32][65];
    int blk = blockIdx.x;            // 128 l-tiles * 8 h-tiles * 8 b
    int lt = blk & 127, ht = (blk >> 7) & 7, b = blk >> 10;
    int t = threadIdx.x;
    int ho = t & 63, li = t >> 6;
    #pragma unroll
    for (int it = 0; it < 8; ++it) {
        int l = it * 4 + li;
        tl[l][ho] = u[(size_t)(b * L_SEQ + lt * 32 + l) * H_DIM + ht * 64 + ho];
    }
    __syncthreads();
    int hh = t >> 2, lrun = (t & 3) * 8;
    bf16x8 v;
    #pragma unroll
    for (int i = 0; i < 8; ++i) v[i] = (__bf16)tl[lrun + i][hh];
    *(bf16x8*)(ut + (size_t)(ht * 64 + hh) * 32768 + b * 4096 + lt * 32 + lrun) = v;
}

// ---------------- K1: per-chunk end states from ut (bf16 streaming) ----------------
template<int DIR>
__device__ __forceinline__ void state_body(
    int tid, const __bf16* __restrict__ ut, const float* __restrict__ pA,
    __bf16* __restrict__ S)
{
    int q = tid & 3, h = (tid >> 2) & 511, c = (tid >> 11) & 15, b = (tid >> 15) & 7;
    const f32x4* Ap = (const f32x4*)(pA + (size_t)(DIR * 512 + h) * 64 + q * 16);
    float A[16], x[16];
    #pragma unroll
    for (int i = 0; i < 4; ++i) {
        f32x4 a = Ap[i];
        A[4*i+0]=a[0]; A[4*i+1]=a[1]; A[4*i+2]=a[2]; A[4*i+3]=a[3];
        x[4*i+0]=0.f;  x[4*i+1]=0.f;  x[4*i+2]=0.f;  x[4*i+3]=0.f;
    }
    int off = h * 32768 + b * 4096 + (DIR ? (c * 256 + 248) : c * 256);
    const int vstep = DIR ? -8 : 8;
    bf16x8 v = *(const bf16x8*)(ut + off);
    for (int blk = 0; blk < 31; ++blk) {
        off += vstep;
        bf16x8 nv = *(const bf16x8*)(ut + off);
        #pragma unroll
        for (int jj = 0; jj < 8; ++jj) {
            float cur = (float)v[DIR ? 7 - jj : jj];
            #pragma unroll
            for (int i = 0; i < 16; ++i) x[i] = fmaf(A[i], x[i], cur);
        }
        v = nv;
    }
    #pragma unroll
    for (int jj = 0; jj < 8; ++jj) {
        float cur = (float)v[DIR ? 7 - jj : jj];
        #pragma unroll
        for (int i = 0; i < 16; ++i) x[i] = fmaf(A[i], x[i], cur);
    }
    size_t soff = ((((size_t)DIR * N_CH + c) * N_B + b) * H_DIM + h) * N_ST + q * 16;
    bf16x8 o0, o1;
    #pragma unroll
    for (int i = 0; i < 8; ++i) { o0[i] = (__bf16)x[i]; o1[i] = (__bf16)x[8 + i]; }
    *(bf16x8*)(S + soff) = o0;
    *(bf16x8*)(S + soff + 8) = o1;
}

__global__ __launch_bounds__(256) void k_state(
    const __bf16* __restrict__ ut, const float* __restrict__ pA,
    __bf16* __restrict__ S)
{
    int tid = blockIdx.x * 256 + threadIdx.x;      // 524288
    if (tid >> 18) state_body<1>(tid, ut, pA, S);
    else           state_body<0>(tid, ut, pA, S);
}

// ---------------- K2: inter-chunk scan (bf16 S, in place) ----------------
// dir 0: ascending prefix scan; dir 1: descending suffix scan (reverse flow).
__global__ __launch_bounds__(256) void k_chunkscan(
    const float* __restrict__ pPW, __bf16* __restrict__ S)
{
    int tid = blockIdx.x * 256 + threadIdx.x;      // 524288
    int n   = tid & 63;
    int h   = (tid >> 6) & 511;
    int b   = (tid >> 15) & 7;
    int dir = tid >> 18;
    float pw = pPW[((size_t)(dir * H_DIM + h)) * N_ST + n];
    float X = 0.f;
    for (int i = 0; i < N_CH; ++i) {
        int c = dir ? (N_CH - 1 - i) : i;
        size_t a = ((((size_t)dir * N_CH + c) * N_B + b) * H_DIM + h) * N_ST + n;
        float tmp = (float)S[a];
        S[a] = (__bf16)X;                 // incoming state for chunk c
        X = fmaf(pw, X, tmp);
    }
}

// ---------------- k_conv: MFMA chunk conv  y = Toep(k)@u + G@x0 + D*u ----------------
// 512 threads / 8 waves per block, one (dir,h) each. Barrier-free main loop:
// B-frags direct from L2-resident ut; A-frags = 2x ds_read_b64 from packed
// ascending tap table; triangular jt skip per wave.
template<int DIR>
__device__ __forceinline__ void conv_body(
    int h, int t,
    const float* __restrict__ kk, const float* __restrict__ pLG,
    const float* __restrict__ pCB, const float* __restrict__ Dv,
    const __bf16* __restrict__ ut, const __bf16* __restrict__ S,
    __bf16* __restrict__ ycT,
    unsigned short* asc, ull* kkq8, __bf16 (*G)[72], float* slg, float* scb)
{
    int dirh = DIR * 512 + h;
    int lane = t & 63, w = t >> 6;
    int lr = lane & 15, lg = lane >> 4;
    int wr = (w >> 1) * 64, wc = (w & 1) * 64;

    // --- build ascending tap table: asc[i] = f(271-i) fwd / f(i-272) rev ---
    for (int i = t; i < 548; i += 512) {
        int d = DIR ? (i - 272) : (271 - i);
        float kv = (d >= 0 && d < 256) ? kk[dirh * 256 + d] : 0.f;
        asc[i] = __builtin_bit_cast(unsigned short, (__bf16)kv);
    }
    if (t < 64)              slg[t]      = pLG[dirh * 64 + t];
    else if (t < 128)        scb[t - 64] = pCB[dirh * 64 + (t - 64)];
    __syncthreads();
    // --- pack taps into u64 quads; build G[l][n] = CB_n * A_n^e ---
    for (int i = t; i < 544; i += 512) {
        ull v = (ull)asc[i] | ((ull)asc[i+1] << 16) | ((ull)asc[i+2] << 32)
              | ((ull)asc[i+3] << 48);
        kkq8[i] = v;
    }
    {
        int gl = t & 255, nh = (t >> 8) * 32;
        float e = DIR ? (float)(256 - gl) : (float)(gl + 1);
        #pragma unroll
        for (int n0 = 0; n0 < 32; n0 += 8) {
            bf16x8 g;
            #pragma unroll
            for (int i = 0; i < 8; ++i)
                g[i] = (__bf16)(scb[nh + n0 + i] * exp2f(e * slg[nh + n0 + i]));
            *(bf16x8*)&G[gl][nh + n0] = g;
        }
    }
    __syncthreads();

    f32x4 acc[4][4] = {};

    const int jlo = DIR ? (wr >> 5) : 0;
    const int jhi = DIR ? 8 : ((wr >> 5) + 2);
    const int s0  = (DIR ? 272 : 271) + lg * 8 - (wr + lr);
    const __bf16* ubase_p = ut + (size_t)h * 32768 + (wc >> 4) * 4096
                            + lr * 256 + lg * 8;
    const ull* kq = (const ull*)kkq8;

    bf16x8 bvc[4], bvn[4];
    #pragma unroll
    for (int n_ = 0; n_ < 4; ++n_)
        bvc[n_] = *(const bf16x8*)(ubase_p + n_ * 4096 + jlo * 32);

    for (int jt = jlo; jt < jhi; ++jt) {
        if (jt + 1 < jhi) {
            #pragma unroll
            for (int n_ = 0; n_ < 4; ++n_)
                bvn[n_] = *(const bf16x8*)(ubase_p + n_ * 4096 + (jt + 1) * 32);
        }
        #pragma unroll
        for (int m = 0; m < 4; ++m) {
            int si = s0 + jt * 32 - m * 16;
            ull lo = kq[si], hi = kq[si + 4];
            bf16x8 av;
            ((ull*)&av)[0] = lo; ((ull*)&av)[1] = hi;
            #pragma unroll
            for (int n_ = 0; n_ < 4; ++n_)
                acc[m][n_] = __builtin_amdgcn_mfma_f32_16x16x32_bf16(av, bvc[n_], acc[m][n_], 0, 0, 0);
        }
        #pragma unroll
        for (int n_ = 0; n_ < 4; ++n_) bvc[n_] = bvn[n_];
    }

    // --- state injection: 2 K-tiles over n, B-frags from S (suffix/prefix-scanned) ---
    #pragma unroll
    for (int nt = 0; nt < 2; ++nt) {
        bf16x8 bs[4];
        #pragma unroll
        for (int n_ = 0; n_ < 4; ++n_) {
            size_t soff = ((((size_t)DIR * N_CH + lr) * N_B + ((wc >> 4) + n_)) * H_DIM + h)
                          * N_ST + nt * 32 + lg * 8;
            bs[n_] = *(const bf16x8*)(S + soff);
        }
        #pragma unroll
        for (int m = 0; m < 4; ++m) {
            bf16x8 av = *(const bf16x8*)&G[wr + m * 16 + lr][nt * 32 + lg * 8];
            #pragma unroll
            for (int n_ = 0; n_ < 4; ++n_)
                acc[m][n_] = __builtin_amdgcn_mfma_f32_16x16x32_bf16(av, bs[n_], acc[m][n_], 0, 0, 0);
        }
    }

    // --- epilogue: + D*u, write ycT[dirh][col][l] ---
    float Dh = Dv[h];
    #pragma unroll
    for (int n_ = 0; n_ < 4; ++n_) {
        size_t mb = (size_t)((wc >> 4) + n_) * 4096 + lr * 256;
        #pragma unroll
        for (int m = 0; m < 4; ++m) {
            int l0 = wr + m * 16 + lg * 4;
            bf16x4 uv = *(const bf16x4*)(ut + (size_t)h * 32768 + mb + l0);
            bf16x4 o;
            #pragma unroll
            for (int r = 0; r < 4; ++r)
                o[r] = (__bf16)(acc[m][n_][r] + Dh * (float)uv[r]);
            *(bf16x4*)(ycT + (size_t)dirh * 32768 + mb + l0) = o;
        }
    }
}

__global__ __launch_bounds__(512, 4) void k_conv(
    const float* __restrict__ kk, const float* __restrict__ pLG,
    const float* __restrict__ pCB, const float* __restrict__ Dv,
    const __bf16* __restrict__ ut, const __bf16* __restrict__ S,
    __bf16* __restrict__ ycT)
{
    __shared__ unsigned short asc[548];
    __shared__ ull kkq8[544];
    __shared__ __bf16 G[256][72];
    __shared__ float slg[64], scb[64];
    int h = blockIdx.x & 511;
    int t = threadIdx.x;
    if (blockIdx.x >> 9)
        conv_body<1>(h, t, kk, pLG, pCB, Dv, ut, S, ycT, asc, kkq8, G, slg, scb);
    else
        conv_body<0>(h, t, kk, pLG, pCB, Dv, ut, S, ycT, asc, kkq8, G, slg, scb);
}

// ---------------- K4: out = ycat @ W^T + bias ; A read from ycT[k][m] ----------------
__global__ __launch_bounds__(256) void k_gemm(
    const __bf16* __restrict__ ycT, const __bf16* __restrict__ B,
    const float* __restrict__ bias, float* __restrict__ out)
{
    __shared__ __bf16 As[4][128][8];    // [k>>3][m][k&7], XOR-swizzled
    __shared__ __bf16 Bs[128][32];
    int t  = threadIdx.x;
    int l  = t & 63, w = t >> 6;
    int lr = l & 15, lg = l >> 4;
    int mBase = blockIdx.y * 128;
    int nBase = blockIdx.x * 128;
    int wr = (w >> 1) * 64, wc = (w & 1) * 64;

    int rowL = w * 16 + (l >> 2);
    int kb   = (l & 3) * 8;

    int sT  = t & 15;           // m-group (8 rows each)
    int skk = t >> 4;           // 0..15
    int swz = (sT & 7) << 4;

    char* AsB = (char*)&As[0][0][0];
    f32x4 acc[4][4] = {};

    for (int kt = 0; kt < K_GEMM; kt += 32) {
        __syncthreads();
        {   // B tile via global_load_lds (linear)
            const __bf16* gb0 = B + (size_t)(nBase + rowL) * K_GEMM + kt + kb;
            const __bf16* gb1 = B + (size_t)(nBase + 64 + rowL) * K_GEMM + kt + kb;
            GLOAD16(gb0, ((char*)&Bs[0][0]) + (w * 64) * 16);
            GLOAD16(gb1, ((char*)&Bs[0][0]) + (256 + w * 64) * 16);
        }
        // A tile from ycT[k][m]: reg-staged 16x8 transpose, swizzled writes
        #pragma unroll
        for (int p = 0; p < 2; ++p) {
            int kk_ = skk + p * 16;
            u16x8 av = *(const u16x8*)(ycT + (size_t)(kt + kk_) * 32768 + mBase + sT * 8);
            int kgrp = kk_ >> 3, ke = kk_ & 7;
            #pragma unroll
            for (int i = 0; i < 8; ++i) {
                int off = ((kgrp * 128 + sT * 8 + i) * 16 + ke * 2) ^ swz;
                *(unsigned short*)(AsB + off) = av[i];
            }
        }
        __syncthreads();
        bf16x8 af[4], bfv[4];
        #pragma unroll
        for (int m = 0; m < 4; ++m) {
            int row = wr + m * 16 + lr;
            int off = ((lg * 128 + row) * 16) ^ (((row >> 3) & 7) << 4);
            af[m] = *(const bf16x8*)(AsB + off);
        }
        #pragma unroll
        for (int n = 0; n < 4; ++n) bfv[n] = *(const bf16x8*)&Bs[wc + n * 16 + lr][lg * 8];
        #pragma unroll
        for (int m = 0; m < 4; ++m)
            #pragma unroll
            for (int n = 0; n < 4; ++n)
                acc[m][n] = __builtin_amdgcn_mfma_f32_16x16x32_bf16(af[m], bfv[n], acc[m][n], 0, 0, 0);
    }

    #pragma unroll
    for (int n = 0; n < 4; ++n) {
        int colg = nBase + wc + n * 16 + lr;
        float bv = bias[colg];
        #pragma unroll
        for (int m = 0; m < 4; ++m) {
            int rowg = mBase + wr + m * 16 + lg * 4;
            #pragma unroll
            for (int r = 0; r < 4; ++r)
                out[(size_t)(rowg + r) * H_DIM + colg] = acc[m][n][r] + bv;
        }
    }
}

extern "C" void kernel_launch(void* const* d_in, const int* in_sizes, int n_in,
                              void* d_out, int out_size, void* d_ws, size_t ws_size,
                              hipStream_t stream)
{
    const float* u       = (const float*)d_in[0];
    const float* A_log   = (const float*)d_in[1];
    const float* Bv      = (const float*)d_in[2];
    const float* C       = (const float*)d_in[3];
    const float* D       = (const float*)d_in[4];
    const float* log_dt  = (const float*)d_in[5];
    const float* A_log_r = (const float*)d_in[6];
    const float* B_r     = (const float*)d_in[7];
    const float* C_r     = (const float*)d_in[8];
    const float* W_bi    = (const float*)d_in[9];
    const float* b_bi    = (const float*)d_in[10];
    float* out = (float*)d_out;

    char* ws = (char*)d_ws;
    float* pA   = (float*)(ws + 0x000000);   // 256 KiB
    float* pCB  = (float*)(ws + 0x040000);
    float* pPW  = (float*)(ws + 0x080000);
    float* pLG  = (float*)(ws + 0x0C0000);
    float* kk   = (float*)(ws + 0x100000);   // 1 MiB
    __bf16* Wbf = (__bf16*)(ws + 0x200000);  // 1 MiB
    __bf16* S   = (__bf16*)(ws + 0x300000);  // 16 MiB
    __bf16* ut  = (__bf16*)(ws + 0x1300000); // 32 MiB
    __bf16* ycT = (__bf16*)(ws + 0x3300000); // 64 MiB  (end 115 MiB)

    k_precompute<<<256,  256, 0, stream>>>(A_log, Bv, C, log_dt, A_log_r, B_r, C_r,
                                           pA, pCB, pPW, pLG);
    k_convw     <<<2048, 256, 0, stream>>>(W_bi, Wbf);
    k_kk        <<<1024, 256, 0, stream>>>(pCB, pLG, kk);
    k_ut        <<<8192, 256, 0, stream>>>(u, ut);
    k_state     <<<2048, 256, 0, stream>>>(ut, pA, S);
    k_chunkscan <<<2048, 256, 0, stream>>>(pPW, S);
    k_conv      <<<1024, 512, 0, stream>>>(kk, pLG, pCB, D, ut, S, ycT);
    dim3 g(4, 256);
    k_gemm      <<<g,    256, 0, stream>>>(ycT, Wbf, b_bi, out);
}

// Round 7
// 187.518 us; speedup vs baseline: 1.6053x; 1.2347x over previous
//
#include <hip/hip_runtime.h>
#include <hip/hip_bf16.h>
#include <stdint.h>

#define L_SEQ  4096
#define H_DIM  512
#define N_ST   64
#define N_B    8
#define N_CH   16
#define T_CH   256
#define K_GEMM 1024

typedef float  f32x4  __attribute__((ext_vector_type(4)));
typedef __bf16 bf16x8 __attribute__((ext_vector_type(8)));
typedef __bf16 bf16x4 __attribute__((ext_vector_type(4)));
typedef unsigned short u16x8 __attribute__((ext_vector_type(8)));
typedef unsigned long long ull;

#define GLOAD16(g, l) __builtin_amdgcn_global_load_lds( \
    (const __attribute__((address_space(1))) void*)(g), \
    (__attribute__((address_space(3))) void*)(l), 16, 0, 0)

// ---------------- K0: precompute A_bar, C*B_bar, A_bar^T, log2(A_bar) ----------------
__global__ __launch_bounds__(256) void k_precompute(
    const float* __restrict__ A_log, const float* __restrict__ Bv,
    const float* __restrict__ C, const float* __restrict__ log_dt,
    const float* __restrict__ A_log_r, const float* __restrict__ B_r,
    const float* __restrict__ C_r,
    float* __restrict__ pA, float* __restrict__ pCB, float* __restrict__ pPW,
    float* __restrict__ pLG)
{
    int tid = blockIdx.x * 256 + threadIdx.x;      // 2*512*64
    int n   = tid & 63;
    int h   = (tid >> 6) & 511;
    int dir = tid >> 15;
    float dt = expf(log_dt[h]);
    const float* Al = dir ? A_log_r : A_log;
    const float* Bp = dir ? B_r    : Bv;
    const float* Cp = dir ? C_r    : C;
    float eA = expf(Al[h * N_ST + n]);
    float Ab = expf(-dt * eA);
    float Bb = (1.0f - Ab) / eA * Bp[h * N_ST + n];
    pA[tid]  = Ab;
    pCB[tid] = Cp[h * N_ST + n] * Bb;
    pPW[tid] = expf(-dt * eA * (float)T_CH);
    pLG[tid] = -dt * eA * 1.44269504088896f;       // log2(A_bar)
}

// ---------------- Kw: W_bi f32 -> bf16 ----------------
__global__ __launch_bounds__(256) void k_convw(
    const float* __restrict__ W, __bf16* __restrict__ Wbf)
{
    int tid = blockIdx.x * 256 + threadIdx.x;
    Wbf[tid] = (__bf16)W[tid];
}

// ---------------- k_kk: conv kernel taps kk[dirh][d] = sum_n CB_n A_n^d ----------------
__global__ __launch_bounds__(256) void k_kk(
    const float* __restrict__ pCB, const float* __restrict__ pLG,
    float* __restrict__ kk)
{
    __shared__ float scb[64], slg[64];
    int dirh = blockIdx.x;           // 0..1023
    int d = threadIdx.x;             // 0..255
    if (d < 64) { scb[d] = pCB[dirh * 64 + d]; slg[d] = pLG[dirh * 64 + d]; }
    __syncthreads();
    float s = 0.f;
    #pragma unroll
    for (int n = 0; n < 64; ++n) s += scb[n] * exp2f((float)d * slg[n]);
    kk[dirh * 256 + d] = s;
}

// ---------------- k_ut: u [b,l,h] f32 -> ut [h][b][l] bf16 ----------------
__global__ __launch_bounds__(256) void k_ut(
    const float* __restrict__ u, __bf16* __restrict__ ut)
{
    __shared__ float tl[32][65];
    int blk = blockIdx.x;            // 128 l-tiles * 8 h-tiles * 8 b
    int lt = blk & 127, ht = (blk >> 7) & 7, b = blk >> 10;
    int t = threadIdx.x;
    int ho = t & 63, li = t >> 6;
    #pragma unroll
    for (int it = 0; it < 8; ++it) {
        int l = it * 4 + li;
        tl[l][ho] = u[(size_t)(b * L_SEQ + lt * 32 + l) * H_DIM + ht * 64 + ho];
    }
    __syncthreads();
    int hh = t >> 2, lrun = (t & 3) * 8;
    bf16x8 v;
    #pragma unroll
    for (int i = 0; i < 8; ++i) v[i] = (__bf16)tl[lrun + i][hh];
    *(bf16x8*)(ut + (size_t)(ht * 64 + hh) * 32768 + b * 4096 + lt * 32 + lrun) = v;
}

// ---------------- K1: per-chunk end states from ut (bf16 streaming) ----------------
template<int DIR>
__device__ __forceinline__ void state_body(
    int tid, const __bf16* __restrict__ ut, const float* __restrict__ pA,
    __bf16* __restrict__ S)
{
    int q = tid & 3, h = (tid >> 2) & 511, c = (tid >> 11) & 15, b = (tid >> 15) & 7;
    const f32x4* Ap = (const f32x4*)(pA + (size_t)(DIR * 512 + h) * 64 + q * 16);
    float A[16], x[16];
    #pragma unroll
    for (int i = 0; i < 4; ++i) {
        f32x4 a = Ap[i];
        A[4*i+0]=a[0]; A[4*i+1]=a[1]; A[4*i+2]=a[2]; A[4*i+3]=a[3];
        x[4*i+0]=0.f;  x[4*i+1]=0.f;  x[4*i+2]=0.f;  x[4*i+3]=0.f;
    }
    int off = h * 32768 + b * 4096 + (DIR ? (c * 256 + 248) : c * 256);
    const int vstep = DIR ? -8 : 8;
    bf16x8 v = *(const bf16x8*)(ut + off);
    for (int blk = 0; blk < 31; ++blk) {
        off += vstep;
        bf16x8 nv = *(const bf16x8*)(ut + off);
        #pragma unroll
        for (int jj = 0; jj < 8; ++jj) {
            float cur = (float)v[DIR ? 7 - jj : jj];
            #pragma unroll
            for (int i = 0; i < 16; ++i) x[i] = fmaf(A[i], x[i], cur);
        }
        v = nv;
    }
    #pragma unroll
    for (int jj = 0; jj < 8; ++jj) {
        float cur = (float)v[DIR ? 7 - jj : jj];
        #pragma unroll
        for (int i = 0; i < 16; ++i) x[i] = fmaf(A[i], x[i], cur);
    }
    size_t soff = ((((size_t)DIR * N_CH + c) * N_B + b) * H_DIM + h) * N_ST + q * 16;
    bf16x8 o0, o1;
    #pragma unroll
    for (int i = 0; i < 8; ++i) { o0[i] = (__bf16)x[i]; o1[i] = (__bf16)x[8 + i]; }
    *(bf16x8*)(S + soff) = o0;
    *(bf16x8*)(S + soff + 8) = o1;
}

__global__ __launch_bounds__(256) void k_state(
    const __bf16* __restrict__ ut, const float* __restrict__ pA,
    __bf16* __restrict__ S)
{
    int tid = blockIdx.x * 256 + threadIdx.x;      // 524288
    if (tid >> 18) state_body<1>(tid, ut, pA, S);
    else           state_body<0>(tid, ut, pA, S);
}

// ---------------- K2: inter-chunk scan (bf16 S, in place) ----------------
__global__ __launch_bounds__(256) void k_chunkscan(
    const float* __restrict__ pPW, __bf16* __restrict__ S)
{
    int tid = blockIdx.x * 256 + threadIdx.x;      // 524288
    int n   = tid & 63;
    int h   = (tid >> 6) & 511;
    int b   = (tid >> 15) & 7;
    int dir = tid >> 18;
    float pw = pPW[((size_t)(dir * H_DIM + h)) * N_ST + n];
    float X = 0.f;
    for (int i = 0; i < N_CH; ++i) {
        int c = dir ? (N_CH - 1 - i) : i;
        size_t a = ((((size_t)dir * N_CH + c) * N_B + b) * H_DIM + h) * N_ST + n;
        float tmp = (float)S[a];
        S[a] = (__bf16)X;                 // incoming state for chunk c
        X = fmaf(pw, X, tmp);
    }
}

// ---------------- k_conv v3: LDS-staged MFMA chunk conv ----------------
// 512 thr / 8 waves, one (dir,h). ut[h] slab staged in two 32KB halves into
// LDS (linear dest, inverse-swizzled source: chunk ^= col&7). Wave w owns
// row-tiles {w, 15-w} (balanced band). G-frags computed on the fly (exp2).
template<int DIR>
__device__ __forceinline__ void conv_body(
    int h, int t,
    const float* __restrict__ kk, const float* __restrict__ pLG,
    const float* __restrict__ pCB, const float* __restrict__ Dv,
    const __bf16* __restrict__ ut, const __bf16* __restrict__ S,
    __bf16* __restrict__ ycT,
    __bf16* uts, ull* kkq8, float* slg, float* scb)
{
    int dirh = DIR * 512 + h;
    int lane = t & 63, w = t >> 6;
    int lr = lane & 15, lg = lane >> 4;

    // taps (ascending-read order) built in the uts region, then packed into
    // overlapping u64 windows kkq8[i] = asc[i..i+4).
    unsigned short* asc = (unsigned short*)uts;
    for (int i = t; i < 548; i += 512) {
        int d = DIR ? (i - 272) : (271 - i);
        float kv = (d >= 0 && d < 256) ? kk[dirh * 256 + d] : 0.f;
        asc[i] = __builtin_bit_cast(unsigned short, (__bf16)kv);
    }
    if (t < 64)       slg[t]      = pLG[dirh * 64 + t];
    else if (t < 128) scb[t - 64] = pCB[dirh * 64 + (t - 64)];
    __syncthreads();
    for (int i = t; i < 544; i += 512)
        kkq8[i] = (ull)asc[i] | ((ull)asc[i+1] << 16) | ((ull)asc[i+2] << 32)
                | ((ull)asc[i+3] << 48);
    __syncthreads();

    float Dh = Dv[h];
    const ull* kq = kkq8;

    for (int hf = 0; hf < 2; ++hf) {
        // ---- stage 64 cols x 256 l (32 KB), swizzled ----
        #pragma unroll
        for (int i = 0; i < 4; ++i) {
            int chunk = i * 512 + t;          // 0..2047
            int col   = chunk >> 5;
            int l8    = (chunk & 31) << 3;
            int l8s   = l8 ^ ((col & 7) << 3);
            GLOAD16(ut + (size_t)h * 32768 + (hf * 64 + col) * 256 + l8s,
                    (char*)uts + chunk * 16);
        }
        __syncthreads();

        f32x4 acc[2][4] = {};

        // ---- Toeplitz band ----
        #pragma unroll
        for (int mf = 0; mf < 2; ++mf) {
            int rt  = mf ? (15 - w) : w;
            int jlo = DIR ? (rt >> 1) : 0;
            int jhi = DIR ? 8 : ((rt >> 1) + 1);
            int sb  = (DIR ? 272 : 271) + lg * 8 - rt * 16 - lr;
            for (int jt = jlo; jt < jhi; ++jt) {
                bf16x8 bv[4];
                #pragma unroll
                for (int n = 0; n < 4; ++n) {
                    int col = n * 16 + lr;
                    bv[n] = *(const bf16x8*)((char*)uts + col * 512
                              + (((jt * 4 + lg) ^ (col & 7)) << 4));
                }
                int si = sb + jt * 32;
                ull lo = kq[si], hi = kq[si + 4];
                bf16x8 av;
                ((ull*)&av)[0] = lo; ((ull*)&av)[1] = hi;
                #pragma unroll
                for (int n = 0; n < 4; ++n)
                    acc[mf][n] = __builtin_amdgcn_mfma_f32_16x16x32_bf16(av, bv[n], acc[mf][n], 0, 0, 0);
            }
        }

        // ---- state injection (G on the fly) ----
        #pragma unroll
        for (int nt = 0; nt < 2; ++nt) {
            bf16x8 bs[4];
            #pragma unroll
            for (int n = 0; n < 4; ++n) {
                size_t soff = ((((size_t)DIR * N_CH + lr) * N_B + (hf * 4 + n)) * H_DIM + h)
                              * N_ST + nt * 32 + lg * 8;
                bs[n] = *(const bf16x8*)(S + soff);
            }
            #pragma unroll
            for (int mf = 0; mf < 2; ++mf) {
                int rt = mf ? (15 - w) : w;
                int l  = rt * 16 + lr;
                float e = DIR ? (float)(256 - l) : (float)(l + 1);
                bf16x8 gv;
                #pragma unroll
                for (int j = 0; j < 8; ++j) {
                    int n = nt * 32 + lg * 8 + j;
                    gv[j] = (__bf16)(scb[n] * exp2f(e * slg[n]));
                }
                #pragma unroll
                for (int n = 0; n < 4; ++n)
                    acc[mf][n] = __builtin_amdgcn_mfma_f32_16x16x32_bf16(gv, bs[n], acc[mf][n], 0, 0, 0);
            }
        }

        // ---- epilogue: + D*u, write ycT ----
        #pragma unroll
        for (int mf = 0; mf < 2; ++mf) {
            int rt = mf ? (15 - w) : w;
            int l0 = rt * 16 + lg * 4;
            #pragma unroll
            for (int n = 0; n < 4; ++n) {
                int col = n * 16 + lr;
                bf16x4 uv = *(const bf16x4*)((char*)uts + col * 512
                             + ((((l0 >> 3) ^ (col & 7)) << 4) | ((l0 & 7) * 2)));
                bf16x4 o;
                #pragma unroll
                for (int r = 0; r < 4; ++r)
                    o[r] = (__bf16)(acc[mf][n][r] + Dh * (float)uv[r]);
                *(bf16x4*)(ycT + (size_t)dirh * 32768 + (hf * 64 + col) * 256 + l0) = o;
            }
        }
        __syncthreads();   // protect uts before next half's staging
    }
}

__global__ __launch_bounds__(512, 4) void k_conv(
    const float* __restrict__ kk, const float* __restrict__ pLG,
    const float* __restrict__ pCB, const float* __restrict__ Dv,
    const __bf16* __restrict__ ut, const __bf16* __restrict__ S,
    __bf16* __restrict__ ycT)
{
    __shared__ __bf16 uts[16384];      // 32 KB (also hosts asc during setup)
    __shared__ ull kkq8[544];
    __shared__ float slg[64], scb[64];
    int h = blockIdx.x & 511;
    int t = threadIdx.x;
    if (blockIdx.x >> 9)
        conv_body<1>(h, t, kk, pLG, pCB, Dv, ut, S, ycT, uts, kkq8, slg, scb);
    else
        conv_body<0>(h, t, kk, pLG, pCB, Dv, ut, S, ycT, uts, kkq8, slg, scb);
}

// ---------------- K4: out = ycat @ W^T + bias ; A from ycT[k][m], N-tile 256 ----------------
__global__ __launch_bounds__(256, 2) void k_gemm(
    const __bf16* __restrict__ ycT, const __bf16* __restrict__ B,
    const float* __restrict__ bias, float* __restrict__ out)
{
    __shared__ __bf16 As[4][128][8];    // [k>>3][m][k&7], XOR-swizzled
    __shared__ __bf16 Bs[256][32];
    int t  = threadIdx.x;
    int l  = t & 63, w = t >> 6;
    int lr = l & 15, lg = l >> 4;
    int mBase = blockIdx.y * 128;
    int nBase = blockIdx.x * 256;
    int wr = (w >> 1) * 64, wc = (w & 1) * 128;

    int sT  = t & 15;           // m-group (8 rows each)
    int skk = t >> 4;           // 0..15
    int swz = (sT & 7) << 4;

    char* AsB = (char*)&As[0][0][0];
    f32x4 acc[4][8] = {};

    for (int kt = 0; kt < K_GEMM; kt += 32) {
        __syncthreads();
        // B tile [256][32] via global_load_lds (linear)
        #pragma unroll
        for (int i = 0; i < 4; ++i) {
            int chunk = i * 256 + t;          // 0..1023
            int row = chunk >> 2, kb = (chunk & 3) * 8;
            GLOAD16(B + (size_t)(nBase + row) * K_GEMM + kt + kb,
                    ((char*)&Bs[0][0]) + chunk * 16);
        }
        // A tile from ycT[k][m]: reg-staged transpose, swizzled writes
        #pragma unroll
        for (int p = 0; p < 2; ++p) {
            int kk_ = skk + p * 16;
            u16x8 av = *(const u16x8*)(ycT + (size_t)(kt + kk_) * 32768 + mBase + sT * 8);
            int kgrp = kk_ >> 3, ke = kk_ & 7;
            #pragma unroll
            for (int i = 0; i < 8; ++i) {
                int off = ((kgrp * 128 + sT * 8 + i) * 16 + ke * 2) ^ swz;
                *(unsigned short*)(AsB + off) = av[i];
            }
        }
        __syncthreads();
        bf16x8 af[4], bfv[8];
        #pragma unroll
        for (int m = 0; m < 4; ++m) {
            int row = wr + m * 16 + lr;
            int off = ((lg * 128 + row) * 16) ^ (((row >> 3) & 7) << 4);
            af[m] = *(const bf16x8*)(AsB + off);
        }
        #pragma unroll
        for (int n = 0; n < 8; ++n) bfv[n] = *(const bf16x8*)&Bs[wc + n * 16 + lr][lg * 8];
        #pragma unroll
        for (int m = 0; m < 4; ++m)
            #pragma unroll
            for (int n = 0; n < 8; ++n)
                acc[m][n] = __builtin_amdgcn_mfma_f32_16x16x32_bf16(af[m], bfv[n], acc[m][n], 0, 0, 0);
    }

    #pragma unroll
    for (int n = 0; n < 8; ++n) {
        int colg = nBase + wc + n * 16 + lr;
        float bv = bias[colg];
        #pragma unroll
        for (int m = 0; m < 4; ++m) {
            int rowg = mBase + wr + m * 16 + lg * 4;
            #pragma unroll
            for (int r = 0; r < 4; ++r)
                out[(size_t)(rowg + r) * H_DIM + colg] = acc[m][n][r] + bv;
        }
    }
}

extern "C" void kernel_launch(void* const* d_in, const int* in_sizes, int n_in,
                              void* d_out, int out_size, void* d_ws, size_t ws_size,
                              hipStream_t stream)
{
    const float* u       = (const float*)d_in[0];
    const float* A_log   = (const float*)d_in[1];
    const float* Bv      = (const float*)d_in[2];
    const float* C       = (const float*)d_in[3];
    const float* D       = (const float*)d_in[4];
    const float* log_dt  = (const float*)d_in[5];
    const float* A_log_r = (const float*)d_in[6];
    const float* B_r     = (const float*)d_in[7];
    const float* C_r     = (const float*)d_in[8];
    const float* W_bi    = (const float*)d_in[9];
    const float* b_bi    = (const float*)d_in[10];
    float* out = (float*)d_out;

    char* ws = (char*)d_ws;
    float* pA   = (float*)(ws + 0x000000);   // 256 KiB
    float* pCB  = (float*)(ws + 0x040000);
    float* pPW  = (float*)(ws + 0x080000);
    float* pLG  = (float*)(ws + 0x0C0000);
    float* kk   = (float*)(ws + 0x100000);   // 1 MiB
    __bf16* Wbf = (__bf16*)(ws + 0x200000);  // 1 MiB
    __bf16* S   = (__bf16*)(ws + 0x300000);  // 16 MiB
    __bf16* ut  = (__bf16*)(ws + 0x1300000); // 32 MiB
    __bf16* ycT = (__bf16*)(ws + 0x3300000); // 64 MiB  (end 115 MiB)

    k_precompute<<<256,  256, 0, stream>>>(A_log, Bv, C, log_dt, A_log_r, B_r, C_r,
                                           pA, pCB, pPW, pLG);
    k_convw     <<<2048, 256, 0, stream>>>(W_bi, Wbf);
    k_kk        <<<1024, 256, 0, stream>>>(pCB, pLG, kk);
    k_ut        <<<8192, 256, 0, stream>>>(u, ut);
    k_state     <<<2048, 256, 0, stream>>>(ut, pA, S);
    k_chunkscan <<<2048, 256, 0, stream>>>(pPW, S);
    k_conv      <<<1024, 512, 0, stream>>>(kk, pLG, pCB, D, ut, S, ycT);
    dim3 g(2, 256);
    k_gemm      <<<g,    256, 0, stream>>>(ycT, Wbf, b_bi, out);
}

// Round 9
// 185.250 us; speedup vs baseline: 1.6249x; 1.0122x over previous
//
#include <hip/hip_runtime.h>
#include <hip/hip_bf16.h>
#include <stdint.h>

#define L_SEQ  4096
#define H_DIM  512
#define N_ST   64
#define N_B    8
#define N_CH   16
#define T_CH   256
#define K_GEMM 1024

typedef float  f32x4  __attribute__((ext_vector_type(4)));
typedef __bf16 bf16x8 __attribute__((ext_vector_type(8)));
typedef __bf16 bf16x4 __attribute__((ext_vector_type(4)));
typedef unsigned short u16x8 __attribute__((ext_vector_type(8)));
typedef unsigned long long ull;

#define GLOAD16(g, l) __builtin_amdgcn_global_load_lds( \
    (const __attribute__((address_space(1))) void*)(g), \
    (__attribute__((address_space(3))) void*)(l), 16, 0, 0)

// ---------------- K0: precompute A_bar, C*B_bar, A_bar^T, log2(A_bar) ----------------
__global__ __launch_bounds__(256) void k_precompute(
    const float* __restrict__ A_log, const float* __restrict__ Bv,
    const float* __restrict__ C, const float* __restrict__ log_dt,
    const float* __restrict__ A_log_r, const float* __restrict__ B_r,
    const float* __restrict__ C_r,
    float* __restrict__ pA, float* __restrict__ pCB, float* __restrict__ pPW,
    float* __restrict__ pLG)
{
    int tid = blockIdx.x * 256 + threadIdx.x;      // 2*512*64
    int n   = tid & 63;
    int h   = (tid >> 6) & 511;
    int dir = tid >> 15;
    float dt = expf(log_dt[h]);
    const float* Al = dir ? A_log_r : A_log;
    const float* Bp = dir ? B_r    : Bv;
    const float* Cp = dir ? C_r    : C;
    float eA = expf(Al[h * N_ST + n]);
    float Ab = expf(-dt * eA);
    float Bb = (1.0f - Ab) / eA * Bp[h * N_ST + n];
    pA[tid]  = Ab;
    pCB[tid] = Cp[h * N_ST + n] * Bb;
    pPW[tid] = expf(-dt * eA * (float)T_CH);
    pLG[tid] = -dt * eA * 1.44269504088896f;       // log2(A_bar)
}

// ---------------- Kw: W_bi f32 -> bf16 ----------------
__global__ __launch_bounds__(256) void k_convw(
    const float* __restrict__ W, __bf16* __restrict__ Wbf)
{
    int tid = blockIdx.x * 256 + threadIdx.x;
    Wbf[tid] = (__bf16)W[tid];
}

// ---------------- k_kk: conv kernel taps kk[dirh][d] = sum_n CB_n A_n^d ----------------
__global__ __launch_bounds__(256) void k_kk(
    const float* __restrict__ pCB, const float* __restrict__ pLG,
    float* __restrict__ kk)
{
    __shared__ float scb[64], slg[64];
    int dirh = blockIdx.x;           // 0..1023
    int d = threadIdx.x;             // 0..255
    if (d < 64) { scb[d] = pCB[dirh * 64 + d]; slg[d] = pLG[dirh * 64 + d]; }
    __syncthreads();
    float s = 0.f;
    #pragma unroll
    for (int n = 0; n < 64; ++n) s += scb[n] * exp2f((float)d * slg[n]);
    kk[dirh * 256 + d] = s;
}

// ---------------- k_ut: u [b,l,h] f32 -> ut [h][b][l] bf16 ----------------
__global__ __launch_bounds__(256) void k_ut(
    const float* __restrict__ u, __bf16* __restrict__ ut)
{
    __shared__ float tl[32][65];
    int blk = blockIdx.x;            // 128 l-tiles * 8 h-tiles * 8 b
    int lt = blk & 127, ht = (blk >> 7) & 7, b = blk >> 10;
    int t = threadIdx.x;
    int ho = t & 63, li = t >> 6;
    #pragma unroll
    for (int it = 0; it < 8; ++it) {
        int l = it * 4 + li;
        tl[l][ho] = u[(size_t)(b * L_SEQ + lt * 32 + l) * H_DIM + ht * 64 + ho];
    }
    __syncthreads();
    int hh = t >> 2, lrun = (t & 3) * 8;
    bf16x8 v;
    #pragma unroll
    for (int i = 0; i < 8; ++i) v[i] = (__bf16)tl[lrun + i][hh];
    *(bf16x8*)(ut + (size_t)(ht * 64 + hh) * 32768 + b * 4096 + lt * 32 + lrun) = v;
}

// ---------------- K1: per-chunk end states from ut (bf16 streaming) ----------------
template<int DIR>
__device__ __forceinline__ void state_body(
    int tid, const __bf16* __restrict__ ut, const float* __restrict__ pA,
    __bf16* __restrict__ S)
{
    int q = tid & 3, h = (tid >> 2) & 511, c = (tid >> 11) & 15, b = (tid >> 15) & 7;
    const f32x4* Ap = (const f32x4*)(pA + (size_t)(DIR * 512 + h) * 64 + q * 16);
    float A[16], x[16];
    #pragma unroll
    for (int i = 0; i < 4; ++i) {
        f32x4 a = Ap[i];
        A[4*i+0]=a[0]; A[4*i+1]=a[1]; A[4*i+2]=a[2]; A[4*i+3]=a[3];
        x[4*i+0]=0.f;  x[4*i+1]=0.f;  x[4*i+2]=0.f;  x[4*i+3]=0.f;
    }
    int off = h * 32768 + b * 4096 + (DIR ? (c * 256 + 248) : c * 256);
    const int vstep = DIR ? -8 : 8;
    bf16x8 v = *(const bf16x8*)(ut + off);
    for (int blk = 0; blk < 31; ++blk) {
        off += vstep;
        bf16x8 nv = *(const bf16x8*)(ut + off);
        #pragma unroll
        for (int jj = 0; jj < 8; ++jj) {
            float cur = (float)v[DIR ? 7 - jj : jj];
            #pragma unroll
            for (int i = 0; i < 16; ++i) x[i] = fmaf(A[i], x[i], cur);
        }
        v = nv;
    }
    #pragma unroll
    for (int jj = 0; jj < 8; ++jj) {
        float cur = (float)v[DIR ? 7 - jj : jj];
        #pragma unroll
        for (int i = 0; i < 16; ++i) x[i] = fmaf(A[i], x[i], cur);
    }
    size_t soff = ((((size_t)DIR * N_CH + c) * N_B + b) * H_DIM + h) * N_ST + q * 16;
    bf16x8 o0, o1;
    #pragma unroll
    for (int i = 0; i < 8; ++i) { o0[i] = (__bf16)x[i]; o1[i] = (__bf16)x[8 + i]; }
    *(bf16x8*)(S + soff) = o0;
    *(bf16x8*)(S + soff + 8) = o1;
}

__global__ __launch_bounds__(256) void k_state(
    const __bf16* __restrict__ ut, const float* __restrict__ pA,
    __bf16* __restrict__ S)
{
    int tid = blockIdx.x * 256 + threadIdx.x;      // 524288
    if (tid >> 18) state_body<1>(tid, ut, pA, S);
    else           state_body<0>(tid, ut, pA, S);
}

// ---------------- K2: inter-chunk scan (bf16 S, in place) ----------------
__global__ __launch_bounds__(256) void k_chunkscan(
    const float* __restrict__ pPW, __bf16* __restrict__ S)
{
    int tid = blockIdx.x * 256 + threadIdx.x;      // 524288
    int n   = tid & 63;
    int h   = (tid >> 6) & 511;
    int b   = (tid >> 15) & 7;
    int dir = tid >> 18;
    float pw = pPW[((size_t)(dir * H_DIM + h)) * N_ST + n];
    float X = 0.f;
    for (int i = 0; i < N_CH; ++i) {
        int c = dir ? (N_CH - 1 - i) : i;
        size_t a = ((((size_t)dir * N_CH + c) * N_B + b) * H_DIM + h) * N_ST + n;
        float tmp = (float)S[a];
        S[a] = (__bf16)X;                 // incoming state for chunk c
        X = fmaf(pw, X, tmp);
    }
}

// ---------------- k_conv v3: LDS-staged MFMA chunk conv (unchanged) ----------------
template<int DIR>
__device__ __forceinline__ void conv_body(
    int h, int t,
    const float* __restrict__ kk, const float* __restrict__ pLG,
    const float* __restrict__ pCB, const float* __restrict__ Dv,
    const __bf16* __restrict__ ut, const __bf16* __restrict__ S,
    __bf16* __restrict__ ycT,
    __bf16* uts, ull* kkq8, float* slg, float* scb)
{
    int dirh = DIR * 512 + h;
    int lane = t & 63, w = t >> 6;
    int lr = lane & 15, lg = lane >> 4;

    unsigned short* asc = (unsigned short*)uts;
    for (int i = t; i < 548; i += 512) {
        int d = DIR ? (i - 272) : (271 - i);
        float kv = (d >= 0 && d < 256) ? kk[dirh * 256 + d] : 0.f;
        asc[i] = __builtin_bit_cast(unsigned short, (__bf16)kv);
    }
    if (t < 64)       slg[t]      = pLG[dirh * 64 + t];
    else if (t < 128) scb[t - 64] = pCB[dirh * 64 + (t - 64)];
    __syncthreads();
    for (int i = t; i < 544; i += 512)
        kkq8[i] = (ull)asc[i] | ((ull)asc[i+1] << 16) | ((ull)asc[i+2] << 32)
                | ((ull)asc[i+3] << 48);
    __syncthreads();

    float Dh = Dv[h];
    const ull* kq = kkq8;

    for (int hf = 0; hf < 2; ++hf) {
        #pragma unroll
        for (int i = 0; i < 4; ++i) {
            int chunk = i * 512 + t;          // 0..2047
            int col   = chunk >> 5;
            int l8    = (chunk & 31) << 3;
            int l8s   = l8 ^ ((col & 7) << 3);
            GLOAD16(ut + (size_t)h * 32768 + (hf * 64 + col) * 256 + l8s,
                    (char*)uts + chunk * 16);
        }
        __syncthreads();

        f32x4 acc[2][4] = {};

        #pragma unroll
        for (int mf = 0; mf < 2; ++mf) {
            int rt  = mf ? (15 - w) : w;
            int jlo = DIR ? (rt >> 1) : 0;
            int jhi = DIR ? 8 : ((rt >> 1) + 1);
            int sb  = (DIR ? 272 : 271) + lg * 8 - rt * 16 - lr;
            for (int jt = jlo; jt < jhi; ++jt) {
                bf16x8 bv[4];
                #pragma unroll
                for (int n = 0; n < 4; ++n) {
                    int col = n * 16 + lr;
                    bv[n] = *(const bf16x8*)((char*)uts + col * 512
                              + (((jt * 4 + lg) ^ (col & 7)) << 4));
                }
                int si = sb + jt * 32;
                ull lo = kq[si], hi = kq[si + 4];
                bf16x8 av;
                ((ull*)&av)[0] = lo; ((ull*)&av)[1] = hi;
                #pragma unroll
                for (int n = 0; n < 4; ++n)
                    acc[mf][n] = __builtin_amdgcn_mfma_f32_16x16x32_bf16(av, bv[n], acc[mf][n], 0, 0, 0);
            }
        }

        #pragma unroll
        for (int nt = 0; nt < 2; ++nt) {
            bf16x8 bs[4];
            #pragma unroll
            for (int n = 0; n < 4; ++n) {
                size_t soff = ((((size_t)DIR * N_CH + lr) * N_B + (hf * 4 + n)) * H_DIM + h)
                              * N_ST + nt * 32 + lg * 8;
                bs[n] = *(const bf16x8*)(S + soff);
            }
            #pragma unroll
            for (int mf = 0; mf < 2; ++mf) {
                int rt = mf ? (15 - w) : w;
                int l  = rt * 16 + lr;
                float e = DIR ? (float)(256 - l) : (float)(l + 1);
                bf16x8 gv;
                #pragma unroll
                for (int j = 0; j < 8; ++j) {
                    int n = nt * 32 + lg * 8 + j;
                    gv[j] = (__bf16)(scb[n] * exp2f(e * slg[n]));
                }
                #pragma unroll
                for (int n = 0; n < 4; ++n)
                    acc[mf][n] = __builtin_amdgcn_mfma_f32_16x16x32_bf16(gv, bs[n], acc[mf][n], 0, 0, 0);
            }
        }

        #pragma unroll
        for (int mf = 0; mf < 2; ++mf) {
            int rt = mf ? (15 - w) : w;
            int l0 = rt * 16 + lg * 4;
            #pragma unroll
            for (int n = 0; n < 4; ++n) {
                int col = n * 16 + lr;
                bf16x4 uv = *(const bf16x4*)((char*)uts + col * 512
                             + ((((l0 >> 3) ^ (col & 7)) << 4) | ((l0 & 7) * 2)));
                bf16x4 o;
                #pragma unroll
                for (int r = 0; r < 4; ++r)
                    o[r] = (__bf16)(acc[mf][n][r] + Dh * (float)uv[r]);
                *(bf16x4*)(ycT + (size_t)dirh * 32768 + (hf * 64 + col) * 256 + l0) = o;
            }
        }
        __syncthreads();
    }
}

__global__ __launch_bounds__(512, 4) void k_conv(
    const float* __restrict__ kk, const float* __restrict__ pLG,
    const float* __restrict__ pCB, const float* __restrict__ Dv,
    const __bf16* __restrict__ ut, const __bf16* __restrict__ S,
    __bf16* __restrict__ ycT)
{
    __shared__ __bf16 uts[16384];
    __shared__ ull kkq8[544];
    __shared__ float slg[64], scb[64];
    int h = blockIdx.x & 511;
    int t = threadIdx.x;
    if (blockIdx.x >> 9)
        conv_body<1>(h, t, kk, pLG, pCB, Dv, ut, S, ycT, uts, kkq8, slg, scb);
    else
        conv_body<0>(h, t, kk, pLG, pCB, Dv, ut, S, ycT, uts, kkq8, slg, scb);
}

// ---------------- K4 v4: out = ycat @ W^T + bias ----------------
// R7 verified A path (scalar-transpose into swizzled As[4][128][8]) +
// Bs XOR-swizzle (pre-swizzled global source, swizzled reads) +
// A-reg prefetch under MFMA. N-tile 256.
__global__ __launch_bounds__(256, 2) void k_gemm(
    const __bf16* __restrict__ ycT, const __bf16* __restrict__ B,
    const float* __restrict__ bias, float* __restrict__ out)
{
    __shared__ __bf16 As[4][128][8];    // 8 KB, [k>>3][m][k&7], XOR-swizzled
    __shared__ __bf16 Bs[256][32];      // 16 KB, unit-XOR swizzled
    int t  = threadIdx.x;
    int l  = t & 63, w = t >> 6;
    int lr = l & 15, lg = l >> 4;
    int mBase = blockIdx.y * 128;
    int nBase = blockIdx.x * 256;
    int wr = (w >> 1) * 64, wc = (w & 1) * 128;

    int sT  = t & 15;           // m-octet
    int skk = t >> 4;           // k 0..15
    int swz = (sT & 7) << 4;

    char* AsB = (char*)&As[0][0][0];
    char* BsB = (char*)&Bs[0][0];
    f32x4 acc[4][8] = {};

    const __bf16* aptr = ycT + mBase + sT * 8;
    u16x8 a0 = *(const u16x8*)(aptr + (size_t)skk * 32768);
    u16x8 a1 = *(const u16x8*)(aptr + (size_t)(skk + 16) * 32768);

    for (int kt = 0; kt < K_GEMM; kt += 32) {
        __syncthreads();
        // A tile: reg-staged transpose, swizzled scalar writes (R7 verified)
        #pragma unroll
        for (int p = 0; p < 2; ++p) {
            int kk_ = skk + p * 16;
            u16x8 av = p ? a1 : a0;
            int kgrp = kk_ >> 3, ke = kk_ & 7;
            #pragma unroll
            for (int i = 0; i < 8; ++i) {
                int off = ((kgrp * 128 + sT * 8 + i) * 16 + ke * 2) ^ swz;
                *(unsigned short*)(AsB + off) = av[i];
            }
        }
        // B tile via global_load_lds, source pre-swizzled: kq ^= (row>>1)&3
        #pragma unroll
        for (int i = 0; i < 4; ++i) {
            int chunk = i * 256 + t;          // 0..1023
            int row = chunk >> 2, kq = chunk & 3;
            int kqs = kq ^ ((row >> 1) & 3);
            GLOAD16(B + (size_t)(nBase + row) * K_GEMM + kt + kqs * 8,
                    BsB + chunk * 16);
        }
        __syncthreads();
        // prefetch next A tile into regs (in flight under MFMA)
        if (kt + 32 < K_GEMM) {
            a0 = *(const u16x8*)(aptr + (size_t)(kt + 32 + skk) * 32768);
            a1 = *(const u16x8*)(aptr + (size_t)(kt + 48 + skk) * 32768);
        }
        bf16x8 af[4], bfv[8];
        #pragma unroll
        for (int m = 0; m < 4; ++m) {
            int row = wr + m * 16 + lr;
            int off = ((lg * 128 + row) * 16) ^ (((row >> 3) & 7) << 4);
            af[m] = *(const bf16x8*)(AsB + off);
        }
        #pragma unroll
        for (int n = 0; n < 8; ++n) {
            int row = wc + n * 16 + lr;
            bfv[n] = *(const bf16x8*)(BsB + row * 64
                       + ((lg * 16) ^ (((row >> 1) & 3) << 4)));
        }
        #pragma unroll
        for (int m = 0; m < 4; ++m)
            #pragma unroll
            for (int n = 0; n < 8; ++n)
                acc[m][n] = __builtin_amdgcn_mfma_f32_16x16x32_bf16(af[m], bfv[n], acc[m][n], 0, 0, 0);
    }

    #pragma unroll
    for (int n = 0; n < 8; ++n) {
        int colg = nBase + wc + n * 16 + lr;
        float bv = bias[colg];
        #pragma unroll
        for (int m = 0; m < 4; ++m) {
            int rowg = mBase + wr + m * 16 + lg * 4;
            #pragma unroll
            for (int r = 0; r < 4; ++r)
                out[(size_t)(rowg + r) * H_DIM + colg] = acc[m][n][r] + bv;
        }
    }
}

extern "C" void kernel_launch(void* const* d_in, const int* in_sizes, int n_in,
                              void* d_out, int out_size, void* d_ws, size_t ws_size,
                              hipStream_t stream)
{
    const float* u       = (const float*)d_in[0];
    const float* A_log   = (const float*)d_in[1];
    const float* Bv      = (const float*)d_in[2];
    const float* C       = (const float*)d_in[3];
    const float* D       = (const float*)d_in[4];
    const float* log_dt  = (const float*)d_in[5];
    const float* A_log_r = (const float*)d_in[6];
    const float* B_r     = (const float*)d_in[7];
    const float* C_r     = (const float*)d_in[8];
    const float* W_bi    = (const float*)d_in[9];
    const float* b_bi    = (const float*)d_in[10];
    float* out = (float*)d_out;

    char* ws = (char*)d_ws;
    float* pA   = (float*)(ws + 0x000000);   // 256 KiB
    float* pCB  = (float*)(ws + 0x040000);
    float* pPW  = (float*)(ws + 0x080000);
    float* pLG  = (float*)(ws + 0x0C0000);
    float* kk   = (float*)(ws + 0x100000);   // 1 MiB
    __bf16* Wbf = (__bf16*)(ws + 0x200000);  // 1 MiB
    __bf16* S   = (__bf16*)(ws + 0x300000);  // 16 MiB
    __bf16* ut  = (__bf16*)(ws + 0x1300000); // 32 MiB
    __bf16* ycT = (__bf16*)(ws + 0x3300000); // 64 MiB  (end 115 MiB)

    k_precompute<<<256,  256, 0, stream>>>(A_log, Bv, C, log_dt, A_log_r, B_r, C_r,
                                           pA, pCB, pPW, pLG);
    k_convw     <<<2048, 256, 0, stream>>>(W_bi, Wbf);
    k_kk        <<<1024, 256, 0, stream>>>(pCB, pLG, kk);
    k_ut        <<<8192, 256, 0, stream>>>(u, ut);
    k_state     <<<2048, 256, 0, stream>>>(ut, pA, S);
    k_chunkscan <<<2048, 256, 0, stream>>>(pPW, S);
    k_conv      <<<1024, 512, 0, stream>>>(kk, pLG, pCB, D, ut, S, ycT);
    dim3 g(2, 256);
    k_gemm      <<<g,    256, 0, stream>>>(ycT, Wbf, b_bi, out);
}